// Round 5
// baseline (137.296 us; speedup 1.0000x reference)
//
#include <hip/hip_runtime.h>
#include <math.h>

#define N_NODES 2048
#define N_EDGES 4096
#define PI_F 3.14159265358979323846f
#define TWO_PI_F 6.28318530717958647692f

#define EDGE_BLKS 16            // blocks 0..15: 4096 edge threads
#define NODE_BLKS 8             // blocks 16..23: 2048 node threads (also scan)
#define TOTAL_BLKS 256          // 1 block/CU, co-resident by construction
#define SCAN_BLKS (TOTAL_BLKS - EDGE_BLKS)     // 240 blocks participate in scan
#define SCAN_STRIDE (SCAN_BLKS * 256)          // 61440 scan threads
#define TOT4 (N_NODES * N_EDGES / 4)           // 2,097,152 float4s per matrix

// ---- device-coherent (cross-XCD) scalar access: bypass non-coherent L1/L2.
__device__ __forceinline__ float agent_load(const float* p) {
    return __hip_atomic_load(p, __ATOMIC_RELAXED, __HIP_MEMORY_SCOPE_AGENT);
}
__device__ __forceinline__ int agent_load_i(const int* p) {
    return __hip_atomic_load(p, __ATOMIC_RELAXED, __HIP_MEMORY_SCOPE_AGENT);
}
__device__ __forceinline__ void agent_store(float* p, float v) {
    __hip_atomic_store(p, v, __ATOMIC_RELAXED, __HIP_MEMORY_SCOPE_AGENT);
}
__device__ __forceinline__ void agent_store_i(int* p, int v) {
    __hip_atomic_store(p, v, __ATOMIC_RELAXED, __HIP_MEMORY_SCOPE_AGENT);
}
__device__ __forceinline__ void spin_ge(const int* p, int v) {
    while (__hip_atomic_load(p, __ATOMIC_RELAXED, __HIP_MEMORY_SCOPE_AGENT) < v)
        __builtin_amdgcn_s_sleep(2);
    asm volatile("" ::: "memory");
}
// spin until cell becomes nonzero; value is n+1 (zero region = "not found yet")
__device__ __forceinline__ int spin_idx(const int* p) {
    int v;
    while ((v = agent_load_i(p)) == 0) __builtin_amdgcn_s_sleep(2);
    asm volatile("" ::: "memory");
    return v - 1;
}

// ================= 16-amplitude 4-wire sub-circuit =================
// Bit map: wire W0->bit8, W1->bit4, W2->bit2, W3->bit1.
// Gate template (both circuit families factorize to this; verified against
// EDGE_OPS/NODE_OPS gate-by-gate, r4 bench absmax=0):
//   RY(t0,W0) RY(t1,W1) CX(W0,W1) RY(t2,W2) RY(t3,W3) CX(W3,W2)
//   RY(t4,W1) RY(t5,W2)
//   A-type: CX(W1,W2) RY(t6,W2)   -> returns <Z_W2>
//   B-type: CX(W2,W1) RY(t6,W1)   -> returns <Z_W1>, <X_W1>

template<int M>
__device__ __forceinline__ void ry16(float* a, float c, float s) {
#pragma unroll
    for (int i = 0; i < 16; ++i)
        if (!(i & M)) {
            int j = i | M;
            float x0 = a[i], x1 = a[j];
            a[i] = c * x0 - s * x1;
            a[j] = s * x0 + c * x1;
        }
}
template<int MC, int MT>
__device__ __forceinline__ void cx16(float* a) {
#pragma unroll
    for (int i = 0; i < 16; ++i)
        if ((i & MC) && !(i & MT)) {
            int j = i | MT;
            float t = a[i]; a[i] = a[j]; a[j] = t;
        }
}

template<bool BTYPE>
__device__ __forceinline__ void sub16(const float* ic, const float* is,
                                      const float* thc, const float* ths,
                                      float& z, float& x) {
    float a[16];
    a[0] = ic[3]; a[1] = is[3];
#pragma unroll
    for (int i = 0; i < 2; ++i) { a[i | 2] = a[i] * is[2]; a[i] *= ic[2]; }
#pragma unroll
    for (int i = 0; i < 4; ++i) { a[i | 4] = a[i] * is[1]; a[i] *= ic[1]; }
#pragma unroll
    for (int i = 0; i < 8; ++i) { a[i | 8] = a[i] * is[0]; a[i] *= ic[0]; }
    ry16<8>(a, thc[0], ths[0]);
    ry16<4>(a, thc[1], ths[1]);
    cx16<8, 4>(a);
    ry16<2>(a, thc[2], ths[2]);
    ry16<1>(a, thc[3], ths[3]);
    cx16<1, 2>(a);
    ry16<4>(a, thc[4], ths[4]);
    ry16<2>(a, thc[5], ths[5]);
    if (BTYPE) { cx16<2, 4>(a); ry16<4>(a, thc[6], ths[6]); }
    else       { cx16<4, 2>(a); ry16<2>(a, thc[6], ths[6]); }
    const int m = BTYPE ? 4 : 2;
    z = 0.f; x = 0.f;
#pragma unroll
    for (int i = 0; i < 16; ++i) z += (i & m) ? -a[i] * a[i] : a[i] * a[i];
    if (BTYPE) {
#pragma unroll
        for (int i = 0; i < 16; ++i) if (!(i & 4)) x += a[i] * a[i | 4];
        x *= 2.f;
    }
}

// Per-node edge-circuit publishes: zA = <Z2> of A'(h,x0,x1,x2) [node as SENDER],
// (zB,xB) = <Z5>,<X5> of B'(h,x0,x1,x2) [node as RECV].
__device__ __forceinline__ void edge_pub(
        float chh, float shh, const float* cxv, const float* sxv,
        const float* teC, const float* teS,
        float& zA, float& zB, float& xB) {
    float ic[4] = {chh, cxv[0], cxv[1], cxv[2]};
    float is[4] = {shh, sxv[0], sxv[1], sxv[2]};
    float dmy;
    {   // A': thetas te{0,1,2,3,8,9,12}, measure Z on W2
        float thc[7] = {teC[0], teC[1], teC[2], teC[3], teC[8], teC[9], teC[12]};
        float ths[7] = {teS[0], teS[1], teS[2], teS[3], teS[8], teS[9], teS[12]};
        sub16<false>(ic, is, thc, ths, zA, dmy);
    }
    {   // B': thetas te{4,5,6,7,10,11,13}, measure Z,X on W1
        float thc[7] = {teC[4], teC[5], teC[6], teC[7], teC[10], teC[11], teC[13]};
        float ths[7] = {teS[4], teS[5], teS[6], teS[7], teS[10], teS[11], teS[13]};
        sub16<true>(ic, is, thc, ths, zB, xB);
    }
}

// edge scatter: mi[ri] += ev*H[si], mo[si] += ev*H[ri]; drain own vmem queue
// (atomics performed at coherence point), then tick both arrival counters.
__device__ __forceinline__ void scatter8(float ev, const float4& Hs, const float4& Hr,
                                         int si, int ri,
                                         float* __restrict__ macc, int* __restrict__ arr) {
    atomicAdd(&macc[ri*8+0], ev*Hs.x); atomicAdd(&macc[ri*8+1], ev*Hs.y);
    atomicAdd(&macc[ri*8+2], ev*Hs.z); atomicAdd(&macc[ri*8+3], ev*Hs.w);
    atomicAdd(&macc[si*8+4], ev*Hr.x); atomicAdd(&macc[si*8+5], ev*Hr.y);
    atomicAdd(&macc[si*8+6], ev*Hr.z); atomicAdd(&macc[si*8+7], ev*Hr.w);
    asm volatile("s_waitcnt vmcnt(0)" ::: "memory");
    atomicAdd(&arr[ri], 1); atomicAdd(&arr[si], 1);
}

// ================= single fused persistent kernel =================
// blocks 0..15   : edge role (4096 threads, 1 edge each). Start immediately:
//                  spin on own send/recv cells -> it0 scatter DURING the scan.
// blocks 16..23  : node role (2048 threads). Self-init (H,pub0,inited) ->
//                  scan slice -> wait scan_done -> 2 dataflow rounds.
// blocks 24..255 : pure scanners (Ri/Ro one-hot -> send/recv/deg), then exit.
// Index cells hold n+1 (0 = not yet found; zero region covers them).
__global__ __launch_bounds__(256, 1) void k_fused(
        const float* __restrict__ X, const float* __restrict__ Ri,
        const float* __restrict__ Ro, const float* __restrict__ W,
        const float* __restrict__ b, const float* __restrict__ te,
        const float* __restrict__ tn,
        float* __restrict__ H, float* __restrict__ pub,
        int* __restrict__ send, int* __restrict__ recv,
        float* __restrict__ maccA, float* __restrict__ maccB,
        int* __restrict__ arrA, int* __restrict__ arrB,
        int* __restrict__ epoch, int* __restrict__ inited,
        int* __restrict__ deg, int* __restrict__ sdone,
        float* __restrict__ out) {
    int blk = blockIdx.x, tid = threadIdx.x;

    if (blk < EDGE_BLKS) {
        // ================= EDGE thread: e = blk*256 + tid =================
        int e = blk * 256 + tid;
        float c14h, s14h;
        __sincosf(0.5f * te[14], &s14h, &c14h);
        float C14 = c14h*c14h - s14h*s14h;      // cos(te14)
        float S14 = 2.f*c14h*s14h;              // sin(te14)

        int si = spin_idx(send + e);            // appears during scan
        int ri = spin_idx(recv + e);
        spin_ge(inited + si, 1);                // endpoint pub0/H published
        spin_ge(inited + ri, 1);
        float4 Hs, Hr;
        Hs.x = agent_load(H+si*4+0); Hs.y = agent_load(H+si*4+1);
        Hs.z = agent_load(H+si*4+2); Hs.w = agent_load(H+si*4+3);
        Hr.x = agent_load(H+ri*4+0); Hr.y = agent_load(H+ri*4+1);
        Hr.z = agent_load(H+ri*4+2); Hr.w = agent_load(H+ri*4+3);

        // it 0
        float zA = agent_load(&pub[si*4+0]);
        float zB = agent_load(&pub[ri*4+1]);
        float xB = agent_load(&pub[ri*4+2]);
        float ev = 0.5f*(1.f - (C14*zA*zB - S14*xB));
        scatter8(ev, Hs, Hr, si, ri, maccA, arrA);

        // it 1
        spin_ge(epoch + si, 1); spin_ge(epoch + ri, 1);
        zA = agent_load(&pub[si*4+0]);
        zB = agent_load(&pub[ri*4+1]);
        xB = agent_load(&pub[ri*4+2]);
        Hs.x = agent_load(&H[si*4]);
        Hr.x = agent_load(&H[ri*4]);
        ev = 0.5f*(1.f - (C14*zA*zB - S14*xB));
        scatter8(ev, Hs, Hr, si, ri, maccB, arrB);

        // final
        spin_ge(epoch + si, 2); spin_ge(epoch + ri, 2);
        zA = agent_load(&pub[si*4+0]);
        zB = agent_load(&pub[ri*4+1]);
        xB = agent_load(&pub[ri*4+2]);
        out[e] = 0.5f*(1.f - (C14*zA*zB - S14*xB));
        return;
    }

    // ---------------- node self-init (blocks 16..23) ----------------
    bool is_node = (blk < EDGE_BLKS + NODE_BLKS);
    int n = (blk - EDGE_BLKS) * 256 + tid;      // valid iff is_node
    float chh, shh, cxv[3], sxv[3];
    float teC[14], teS[14], tnC[22], tnS[22];
    if (is_node) {
        float x0 = X[n*3+0], x1 = X[n*3+1], x2 = X[n*3+2];
        float z = x0*W[0] + x1*W[1] + x2*W[2] + b[0];
        float sg = 1.0f / (1.0f + __expf(-z));
        float h = sg * TWO_PI_F;
        __sincosf(0.5f*h,  &shh, &chh);
        __sincosf(0.5f*x0, &sxv[0], &cxv[0]);
        __sincosf(0.5f*x1, &sxv[1], &cxv[1]);
        __sincosf(0.5f*x2, &sxv[2], &cxv[2]);
#pragma unroll
        for (int k = 0; k < 14; ++k) __sincosf(0.5f*te[k], &teS[k], &teC[k]);
#pragma unroll
        for (int k = 0; k < 22; ++k) __sincosf(0.5f*tn[k], &tnS[k], &tnC[k]);
        float zA, zB, xB;
        edge_pub(chh, shh, cxv, sxv, teC, teS, zA, zB, xB);
        agent_store(&pub[n*4+0], zA);
        agent_store(&pub[n*4+1], zB);
        agent_store(&pub[n*4+2], xB);
        agent_store(&H[n*4+0], h);
        agent_store(&H[n*4+1], x0);
        agent_store(&H[n*4+2], x2 == x2 ? x1 : x1);   // keep simple: x1
        agent_store(&H[n*4+3], x2);
        asm volatile("s_waitcnt vmcnt(0)" ::: "memory");   // visible...
        agent_store_i(inited + n, 1);                      // ...before flag
    }

    // ---------------- scan slice (blocks 16..255) ----------------
    {
        int gid = (blk - EDGE_BLKS) * 256 + tid;           // 0..61439
        const float4* Ri4 = (const float4*)Ri;
        const float4* Ro4 = (const float4*)Ro;
        for (int t0 = gid; t0 < TOT4; t0 += 4 * SCAN_STRIDE) {
            float4 vi[4], vo[4];
#pragma unroll
            for (int u = 0; u < 4; ++u) {                  // batch loads: 8 in flight
                int t = t0 + u * SCAN_STRIDE;
                if (t < TOT4) { vi[u] = Ri4[t]; vo[u] = Ro4[t]; }
            }
#pragma unroll
            for (int u = 0; u < 4; ++u) {
                int t = t0 + u * SCAN_STRIDE;
                if (t < TOT4) {
                    int base = t * 4;
                    int row = base >> 12;                  // 4096 floats/row
                    int e   = base & (N_EDGES - 1);
                    int cnt = 0;
                    if (vi[u].x != 0.f) { agent_store_i(recv+e+0, row+1); ++cnt; }
                    if (vi[u].y != 0.f) { agent_store_i(recv+e+1, row+1); ++cnt; }
                    if (vi[u].z != 0.f) { agent_store_i(recv+e+2, row+1); ++cnt; }
                    if (vi[u].w != 0.f) { agent_store_i(recv+e+3, row+1); ++cnt; }
                    if (vo[u].x != 0.f) { agent_store_i(send+e+0, row+1); ++cnt; }
                    if (vo[u].y != 0.f) { agent_store_i(send+e+1, row+1); ++cnt; }
                    if (vo[u].z != 0.f) { agent_store_i(send+e+2, row+1); ++cnt; }
                    if (vo[u].w != 0.f) { agent_store_i(send+e+3, row+1); ++cnt; }
                    if (cnt) atomicAdd(&deg[row], cnt);
                }
            }
        }
        asm volatile("s_waitcnt vmcnt(0)" ::: "memory");   // deg/idx stores done
        __syncthreads();
        if (tid == 0) atomicAdd(sdone, 1);
    }
    if (!is_node) return;                                  // pure scanners exit

    // ---------------- node rounds (blocks 16..23) ----------------
    spin_ge(sdone, SCAN_BLKS);                 // deg is final
    int dg = agent_load_i(deg + n);
    float C20 = tnC[20]*tnC[20] - tnS[20]*tnS[20];
    float S20 = 2.f*tnC[20]*tnS[20];

    for (int it = 0; it < 2; ++it) {
        const float* mc_ = it ? maccB : maccA;
        const int*   ar  = it ? arrB  : arrA;
        spin_ge(ar + n, dg);                   // all my edges scattered
        float M[8], mC[8], mS[8];
#pragma unroll
        for (int k = 0; k < 8; ++k) M[k] = agent_load(mc_ + n*8 + k);
#pragma unroll
        for (int k = 0; k < 8; ++k) __sincosf(0.5f*M[k], &mS[k], &mC[k]);
        float zA1, zA2, xA2, zB9, dmy;
        {   // A1 (mi, wires 0-3): tn{0,1,2,3,12,13,18}, <Z2>
            float thc[7] = {tnC[0],tnC[1],tnC[2],tnC[3],tnC[12],tnC[13],tnC[18]};
            float ths[7] = {tnS[0],tnS[1],tnS[2],tnS[3],tnS[12],tnS[13],tnS[18]};
            sub16<false>(&mC[0], &mS[0], thc, ths, zA1, dmy);
        }
        {   // A2 (mo, wires 4-7): tn{4,5,6,7,14,15,19}, <Z5>,<X5>
            float thc[7] = {tnC[4],tnC[5],tnC[6],tnC[7],tnC[14],tnC[15],tnC[19]};
            float ths[7] = {tnS[4],tnS[5],tnS[6],tnS[7],tnS[14],tnS[15],tnS[19]};
            sub16<true>(&mC[4], &mS[4], thc, ths, zA2, xA2);
        }
        {   // B (h,x: wires 8-11): tn{8,9,10,11,16,17,21}, <Z9>
            float ic[4] = {chh, cxv[0], cxv[1], cxv[2]};
            float is[4] = {shh, sxv[0], sxv[1], sxv[2]};
            float thc[7] = {tnC[8],tnC[9],tnC[10],tnC[11],tnC[16],tnC[17],tnC[21]};
            float ths[7] = {tnS[8],tnS[9],tnS[10],tnS[11],tnS[16],tnS[17],tnS[21]};
            sub16<true>(ic, is, thc, ths, zB9, dmy);
        }
        float p9 = (C20*zA1*zA2 - S20*xA2) * zB9;
        float h = PI_F * (1.f - p9);
        __sincosf(0.5f*h, &shh, &chh);
        float zAe, zBe, xBe;
        edge_pub(chh, shh, cxv, sxv, teC, teS, zAe, zBe, xBe);
        agent_store(&pub[n*4+0], zAe);
        agent_store(&pub[n*4+1], zBe);
        agent_store(&pub[n*4+2], xBe);
        agent_store(&H[n*4], h);
        asm volatile("s_waitcnt vmcnt(0)" ::: "memory");   // visible...
        agent_store_i(epoch + n, it + 1);                  // ...before tick
    }
}

extern "C" void kernel_launch(void* const* d_in, const int* in_sizes, int n_in,
                              void* d_out, int out_size, void* d_ws, size_t ws_size,
                              hipStream_t stream) {
    const float* X  = (const float*)d_in[0];
    const float* Ri = (const float*)d_in[1];
    const float* Ro = (const float*)d_in[2];
    const float* W  = (const float*)d_in[3];
    const float* b  = (const float*)d_in[4];
    const float* te = (const float*)d_in[5];
    const float* tn = (const float*)d_in[6];
    float* out = (float*)d_out;

    float* H     = (float*)d_ws;                    // [8192] (16B-aligned)
    float* pub   = H + N_NODES * 4;                 // [8192] zA,zB,xB,- per node
    // ---- zero region: one memset covers idx cells + counters + macc ----
    int*   send  = (int*)(pub + N_NODES * 4);       // [4096]  cells hold n+1
    int*   recv  = send + N_EDGES;                  // [4096]
    float* maccA = (float*)(recv + N_EDGES);        // [16384]
    float* maccB = maccA + N_NODES * 8;             // [16384]
    int*   arrA  = (int*)(maccB + N_NODES * 8);     // [2048]
    int*   arrB  = arrA + N_NODES;                  // [2048]
    int*   epoch = arrB + N_NODES;                  // [2048]
    int*   inited= epoch + N_NODES;                 // [2048]
    int*   deg   = inited + N_NODES;                // [2048]
    int*   sdone = deg + N_NODES;                   // [16]
    size_t zbytes = (size_t)(2*N_EDGES + 4*N_NODES*8 + 5*N_NODES + 16) * 4;

    hipMemsetAsync((void*)send, 0, zbytes, stream);
    k_fused<<<TOTAL_BLKS, 256, 0, stream>>>(X, Ri, Ro, W, b, te, tn,
                                            H, pub, send, recv,
                                            maccA, maccB, arrA, arrB,
                                            epoch, inited, deg, sdone, out);
}

// Round 6
// 128.954 us; speedup vs baseline: 1.0647x; 1.0647x over previous
//
#include <hip/hip_runtime.h>
#include <math.h>

#define N_NODES 2048
#define N_EDGES 4096
#define PI_F 3.14159265358979323846f
#define TWO_PI_F 6.28318530717958647692f

#define NBLK 256                 // 1 block/CU, co-resident by construction
#define NTHR 256
#define NSCAN (NBLK * NTHR)      // 65536 scan threads
#define TOT4 (N_NODES * N_EDGES / 4)   // 2,097,152 float4s per matrix

// ---- device-coherent (cross-XCD) scalar access: bypass non-coherent L1/L2.
__device__ __forceinline__ float agent_load(const float* p) {
    return __hip_atomic_load(p, __ATOMIC_RELAXED, __HIP_MEMORY_SCOPE_AGENT);
}
__device__ __forceinline__ int agent_load_i(const int* p) {
    return __hip_atomic_load(p, __ATOMIC_RELAXED, __HIP_MEMORY_SCOPE_AGENT);
}
__device__ __forceinline__ void agent_store(float* p, float v) {
    __hip_atomic_store(p, v, __ATOMIC_RELAXED, __HIP_MEMORY_SCOPE_AGENT);
}
__device__ __forceinline__ void agent_store_i(int* p, int v) {
    __hip_atomic_store(p, v, __ATOMIC_RELAXED, __HIP_MEMORY_SCOPE_AGENT);
}
__device__ __forceinline__ void spin_ge(const int* p, int v) {
    while (__hip_atomic_load(p, __ATOMIC_RELAXED, __HIP_MEMORY_SCOPE_AGENT) < v)
        __builtin_amdgcn_s_sleep(2);
    asm volatile("" ::: "memory");
}

// ================= 16-amplitude 4-wire sub-circuit =================
// Bit map: wire W0->bit8, W1->bit4, W2->bit2, W3->bit1.
// Gate template (both circuit families factorize to this; verified
// gate-by-gate vs EDGE_OPS/NODE_OPS; r4/r5 bench absmax=0):
//   RY(t0,W0) RY(t1,W1) CX(W0,W1) RY(t2,W2) RY(t3,W3) CX(W3,W2)
//   RY(t4,W1) RY(t5,W2)
//   A-type: CX(W1,W2) RY(t6,W2)   -> returns <Z_W2>
//   B-type: CX(W2,W1) RY(t6,W1)   -> returns <Z_W1>, <X_W1>

template<int M>
__device__ __forceinline__ void ry16(float* a, float c, float s) {
#pragma unroll
    for (int i = 0; i < 16; ++i)
        if (!(i & M)) {
            int j = i | M;
            float x0 = a[i], x1 = a[j];
            a[i] = c * x0 - s * x1;
            a[j] = s * x0 + c * x1;
        }
}
template<int MC, int MT>
__device__ __forceinline__ void cx16(float* a) {
#pragma unroll
    for (int i = 0; i < 16; ++i)
        if ((i & MC) && !(i & MT)) {
            int j = i | MT;
            float t = a[i]; a[i] = a[j]; a[j] = t;
        }
}

template<bool BTYPE>
__device__ __forceinline__ void sub16(const float* ic, const float* is,
                                      const float* thc, const float* ths,
                                      float& z, float& x) {
    float a[16];
    a[0] = ic[3]; a[1] = is[3];
#pragma unroll
    for (int i = 0; i < 2; ++i) { a[i | 2] = a[i] * is[2]; a[i] *= ic[2]; }
#pragma unroll
    for (int i = 0; i < 4; ++i) { a[i | 4] = a[i] * is[1]; a[i] *= ic[1]; }
#pragma unroll
    for (int i = 0; i < 8; ++i) { a[i | 8] = a[i] * is[0]; a[i] *= ic[0]; }
    ry16<8>(a, thc[0], ths[0]);
    ry16<4>(a, thc[1], ths[1]);
    cx16<8, 4>(a);
    ry16<2>(a, thc[2], ths[2]);
    ry16<1>(a, thc[3], ths[3]);
    cx16<1, 2>(a);
    ry16<4>(a, thc[4], ths[4]);
    ry16<2>(a, thc[5], ths[5]);
    if (BTYPE) { cx16<2, 4>(a); ry16<4>(a, thc[6], ths[6]); }
    else       { cx16<4, 2>(a); ry16<2>(a, thc[6], ths[6]); }
    const int m = BTYPE ? 4 : 2;
    z = 0.f; x = 0.f;
#pragma unroll
    for (int i = 0; i < 16; ++i) z += (i & m) ? -a[i] * a[i] : a[i] * a[i];
    if (BTYPE) {
#pragma unroll
        for (int i = 0; i < 16; ++i) if (!(i & 4)) x += a[i] * a[i | 4];
        x *= 2.f;
    }
}

// Per-node edge-circuit publishes: zA = <Z2> of A'(h,x) [node as SENDER],
// (zB,xB) = <Z5>,<X5> of B'(h,x) [node as RECV].
__device__ __forceinline__ void edge_pub(
        float chh, float shh, const float* cxv, const float* sxv,
        const float* teC, const float* teS,
        float& zA, float& zB, float& xB) {
    float ic[4] = {chh, cxv[0], cxv[1], cxv[2]};
    float is[4] = {shh, sxv[0], sxv[1], sxv[2]};
    float dmy;
    {   // A': thetas te{0,1,2,3,8,9,12}, measure Z on W2
        float thc[7] = {teC[0], teC[1], teC[2], teC[3], teC[8], teC[9], teC[12]};
        float ths[7] = {teS[0], teS[1], teS[2], teS[3], teS[8], teS[9], teS[12]};
        sub16<false>(ic, is, thc, ths, zA, dmy);
    }
    {   // B': thetas te{4,5,6,7,10,11,13}, measure Z,X on W1
        float thc[7] = {teC[4], teC[5], teC[6], teC[7], teC[10], teC[11], teC[13]};
        float ths[7] = {teS[4], teS[5], teS[6], teS[7], teS[10], teS[11], teS[13]};
        sub16<true>(ic, is, thc, ths, zB, xB);
    }
}

// edge scatter: mi[ri] += ev*H[si], mo[si] += ev*H[ri]; drain own vmem queue
// (atomics performed at coherence point), then tick both arrival counters.
__device__ __forceinline__ void scatter8(float ev, const float4& Hs, const float4& Hr,
                                         int si, int ri,
                                         float* __restrict__ macc, int* __restrict__ arr) {
    atomicAdd(&macc[ri*8+0], ev*Hs.x); atomicAdd(&macc[ri*8+1], ev*Hs.y);
    atomicAdd(&macc[ri*8+2], ev*Hs.z); atomicAdd(&macc[ri*8+3], ev*Hs.w);
    atomicAdd(&macc[si*8+4], ev*Hr.x); atomicAdd(&macc[si*8+5], ev*Hr.y);
    atomicAdd(&macc[si*8+6], ev*Hr.z); atomicAdd(&macc[si*8+7], ev*Hr.w);
    asm volatile("s_waitcnt vmcnt(0)" ::: "memory");
    atomicAdd(&arr[ri], 1); atomicAdd(&arr[si], 1);
}

// ================= single fused persistent kernel =================
// Phase 1 (ALL 65536 threads): node self-init (blocks 64..95 lane-threads)
//   then full-BW scan of Ri/Ro -> send/recv/deg; drain; tick sdone.
// Phase 2 (wave 0 only): sdone gate, then r4's proven single-wave actors:
//   blocks 0..63  -> edge wave (e = blk*64+lane)
//   blocks 64..95 -> node wave (n = (blk-64)*64+lane)
// Sync: arr/deg (edge->node), epoch (node->edge); all agent-scope, drained
// before ticks. No global barriers, no mid-scan spinning.
__global__ __launch_bounds__(256) void k_fused(
        const float* __restrict__ X, const float* __restrict__ Ri,
        const float* __restrict__ Ro, const float* __restrict__ W,
        const float* __restrict__ b, const float* __restrict__ te,
        const float* __restrict__ tn,
        float* __restrict__ H, float* __restrict__ pub,
        int* __restrict__ send, int* __restrict__ recv,
        float* __restrict__ maccA, float* __restrict__ maccB,
        int* __restrict__ arrA, int* __restrict__ arrB,
        int* __restrict__ epoch, int* __restrict__ deg,
        int* __restrict__ sdone, float* __restrict__ out) {
    int blk = blockIdx.x, tid = threadIdx.x;
    bool edge_actor = (blk < 64)              && (tid < 64);
    bool node_actor = (blk >= 64 && blk < 96) && (tid < 64);

    // ---- per-actor persistent state (lives across the scan) ----
    float chh = 0.f, shh = 0.f, cxv[3], sxv[3];
    float teC[14], teS[14], tnC[22], tnS[22];
    float C14 = 0.f, S14 = 0.f;

    if (edge_actor) {
        float c, s;
        __sincosf(0.5f * te[14], &s, &c);
        C14 = c*c - s*s;                 // cos(te14)
        S14 = 2.f*c*s;                   // sin(te14)
    }
    if (node_actor) {
        int n = (blk - 64) * 64 + tid;
        float x0 = X[n*3+0], x1 = X[n*3+1], x2 = X[n*3+2];
        float z = x0*W[0] + x1*W[1] + x2*W[2] + b[0];
        float sg = 1.0f / (1.0f + __expf(-z));
        float h = sg * TWO_PI_F;
        __sincosf(0.5f*h,  &shh, &chh);
        __sincosf(0.5f*x0, &sxv[0], &cxv[0]);
        __sincosf(0.5f*x1, &sxv[1], &cxv[1]);
        __sincosf(0.5f*x2, &sxv[2], &cxv[2]);
#pragma unroll
        for (int k = 0; k < 14; ++k) __sincosf(0.5f*te[k], &teS[k], &teC[k]);
#pragma unroll
        for (int k = 0; k < 22; ++k) __sincosf(0.5f*tn[k], &tnS[k], &tnC[k]);
        float zA, zB, xB;
        edge_pub(chh, shh, cxv, sxv, teC, teS, zA, zB, xB);
        agent_store(&pub[n*4+0], zA);
        agent_store(&pub[n*4+1], zB);
        agent_store(&pub[n*4+2], xB);
        agent_store(&H[n*4+0], h);
        agent_store(&H[n*4+1], x0);
        agent_store(&H[n*4+2], x1);
        agent_store(&H[n*4+3], x2);
        // drained by the scan's final vmcnt(0) before the sdone tick.
    }

    // ---------------- phase 1: full-grid scan ----------------
    {
        int gid = blk * NTHR + tid;
        const float4* Ri4 = (const float4*)Ri;
        const float4* Ro4 = (const float4*)Ro;
        // TOT4 = 8 * 4 * NSCAN exactly -> 8 iterations, no guards.
#pragma unroll 1
        for (int t0 = gid; t0 < TOT4; t0 += 4 * NSCAN) {
            float4 vi[4], vo[4];
#pragma unroll
            for (int u = 0; u < 4; ++u) {          // 8 loads in flight
                int t = t0 + u * NSCAN;
                vi[u] = Ri4[t]; vo[u] = Ro4[t];
            }
#pragma unroll
            for (int u = 0; u < 4; ++u) {
                int t = t0 + u * NSCAN;
                int base = t * 4;
                int row = base >> 12;              // 4096 floats per row
                int e   = base & (N_EDGES - 1);
                int cnt = 0;
                if (vi[u].x != 0.f) { agent_store_i(recv+e+0, row); ++cnt; }
                if (vi[u].y != 0.f) { agent_store_i(recv+e+1, row); ++cnt; }
                if (vi[u].z != 0.f) { agent_store_i(recv+e+2, row); ++cnt; }
                if (vi[u].w != 0.f) { agent_store_i(recv+e+3, row); ++cnt; }
                if (vo[u].x != 0.f) { agent_store_i(send+e+0, row); ++cnt; }
                if (vo[u].y != 0.f) { agent_store_i(send+e+1, row); ++cnt; }
                if (vo[u].z != 0.f) { agent_store_i(send+e+2, row); ++cnt; }
                if (vo[u].w != 0.f) { agent_store_i(send+e+3, row); ++cnt; }
                if (cnt) atomicAdd(&deg[row], cnt);
            }
        }
        asm volatile("s_waitcnt vmcnt(0)" ::: "memory");   // stores + init drained
        __syncthreads();
        if (tid == 0) atomicAdd(sdone, 1);
    }

    if (!edge_actor && !node_actor) return;        // waves 1..3 + blocks 96..255
    int lane = tid;                                // < 64

    spin_ge(sdone, NBLK);                          // scan fully done everywhere

    if (edge_actor) {
        // ================= EDGE actor: e = blk*64 + lane =================
        int e = blk * 64 + lane;
        int si = agent_load_i(send + e);
        int ri = agent_load_i(recv + e);
        float4 Hs, Hr;
        Hs.x = agent_load(H+si*4+0); Hs.y = agent_load(H+si*4+1);
        Hs.z = agent_load(H+si*4+2); Hs.w = agent_load(H+si*4+3);
        Hr.x = agent_load(H+ri*4+0); Hr.y = agent_load(H+ri*4+1);
        Hr.z = agent_load(H+ri*4+2); Hr.w = agent_load(H+ri*4+3);

        // it 0
        float zA = agent_load(&pub[si*4+0]);
        float zB = agent_load(&pub[ri*4+1]);
        float xB = agent_load(&pub[ri*4+2]);
        float ev = 0.5f*(1.f - (C14*zA*zB - S14*xB));
        scatter8(ev, Hs, Hr, si, ri, maccA, arrA);

        // it 1
        spin_ge(epoch + si, 1); spin_ge(epoch + ri, 1);
        zA = agent_load(&pub[si*4+0]);
        zB = agent_load(&pub[ri*4+1]);
        xB = agent_load(&pub[ri*4+2]);
        Hs.x = agent_load(&H[si*4]);
        Hr.x = agent_load(&H[ri*4]);
        ev = 0.5f*(1.f - (C14*zA*zB - S14*xB));
        scatter8(ev, Hs, Hr, si, ri, maccB, arrB);

        // final
        spin_ge(epoch + si, 2); spin_ge(epoch + ri, 2);
        zA = agent_load(&pub[si*4+0]);
        zB = agent_load(&pub[ri*4+1]);
        xB = agent_load(&pub[ri*4+2]);
        out[e] = 0.5f*(1.f - (C14*zA*zB - S14*xB));
        return;
    }

    // ================= NODE actor: n = (blk-64)*64 + lane =================
    int n = (blk - 64) * 64 + lane;
    int dg = agent_load_i(deg + n);
    float C20 = tnC[20]*tnC[20] - tnS[20]*tnS[20];
    float S20 = 2.f*tnC[20]*tnS[20];

    for (int it = 0; it < 2; ++it) {
        const float* mc_ = it ? maccB : maccA;
        const int*   ar  = it ? arrB  : arrA;
        // zB9 depends only on our own previous h -> compute in the wait shadow
        float zB9, dmy;
        {   // B (h,x: wires 8-11): tn{8,9,10,11,16,17,21}, <Z9>
            float ic[4] = {chh, cxv[0], cxv[1], cxv[2]};
            float is[4] = {shh, sxv[0], sxv[1], sxv[2]};
            float thc[7] = {tnC[8],tnC[9],tnC[10],tnC[11],tnC[16],tnC[17],tnC[21]};
            float ths[7] = {tnS[8],tnS[9],tnS[10],tnS[11],tnS[16],tnS[17],tnS[21]};
            sub16<true>(ic, is, thc, ths, zB9, dmy);
        }
        spin_ge(ar + n, dg);                   // all my edges scattered
        float M[8], mC[8], mS[8];
#pragma unroll
        for (int k = 0; k < 8; ++k) M[k] = agent_load(mc_ + n*8 + k);
#pragma unroll
        for (int k = 0; k < 8; ++k) __sincosf(0.5f*M[k], &mS[k], &mC[k]);
        float zA1, zA2, xA2;
        {   // A1 (mi, wires 0-3): tn{0,1,2,3,12,13,18}, <Z2>
            float thc[7] = {tnC[0],tnC[1],tnC[2],tnC[3],tnC[12],tnC[13],tnC[18]};
            float ths[7] = {tnS[0],tnS[1],tnS[2],tnS[3],tnS[12],tnS[13],tnS[18]};
            sub16<false>(&mC[0], &mS[0], thc, ths, zA1, dmy);
        }
        {   // A2 (mo, wires 4-7): tn{4,5,6,7,14,15,19}, <Z5>,<X5>
            float thc[7] = {tnC[4],tnC[5],tnC[6],tnC[7],tnC[14],tnC[15],tnC[19]};
            float ths[7] = {tnS[4],tnS[5],tnS[6],tnS[7],tnS[14],tnS[15],tnS[19]};
            sub16<true>(&mC[4], &mS[4], thc, ths, zA2, xA2);
        }
        float p9 = (C20*zA1*zA2 - S20*xA2) * zB9;
        float h = PI_F * (1.f - p9);
        __sincosf(0.5f*h, &shh, &chh);
        float zAe, zBe, xBe;
        edge_pub(chh, shh, cxv, sxv, teC, teS, zAe, zBe, xBe);
        agent_store(&pub[n*4+0], zAe);
        agent_store(&pub[n*4+1], zBe);
        agent_store(&pub[n*4+2], xBe);
        agent_store(&H[n*4], h);
        asm volatile("s_waitcnt vmcnt(0)" ::: "memory");   // visible...
        agent_store_i(epoch + n, it + 1);                  // ...before tick
    }
}

extern "C" void kernel_launch(void* const* d_in, const int* in_sizes, int n_in,
                              void* d_out, int out_size, void* d_ws, size_t ws_size,
                              hipStream_t stream) {
    const float* X  = (const float*)d_in[0];
    const float* Ri = (const float*)d_in[1];
    const float* Ro = (const float*)d_in[2];
    const float* W  = (const float*)d_in[3];
    const float* b  = (const float*)d_in[4];
    const float* te = (const float*)d_in[5];
    const float* tn = (const float*)d_in[6];
    float* out = (float*)d_out;

    float* H     = (float*)d_ws;                    // [8192] (16B-aligned)
    float* pub   = H + N_NODES * 4;                 // [8192] zA,zB,xB,- per node
    int*   send  = (int*)(pub + N_NODES * 4);       // [4096] written by scan (all cells)
    int*   recv  = send + N_EDGES;                  // [4096]
    // ---- zero region: one memset covers macc + counters ----
    float* maccA = (float*)(recv + N_EDGES);        // [16384]
    float* maccB = maccA + N_NODES * 8;             // [16384]
    int*   arrA  = (int*)(maccB + N_NODES * 8);     // [2048]
    int*   arrB  = arrA + N_NODES;                  // [2048]
    int*   epoch = arrB + N_NODES;                  // [2048]
    int*   deg   = epoch + N_NODES;                 // [2048]
    int*   sdone = deg + N_NODES;                   // [16]
    size_t zbytes = (size_t)(2*N_NODES*8 + 4*N_NODES + 16) * 4;

    hipMemsetAsync((void*)maccA, 0, zbytes, stream);
    k_fused<<<NBLK, NTHR, 0, stream>>>(X, Ri, Ro, W, b, te, tn,
                                       H, pub, send, recv,
                                       maccA, maccB, arrA, arrB,
                                       epoch, deg, sdone, out);
}

// Round 8
// 128.746 us; speedup vs baseline: 1.0664x; 1.0016x over previous
//
#include <hip/hip_runtime.h>
#include <math.h>

#define N_NODES 2048
#define N_EDGES 4096
#define PI_F 3.14159265358979323846f
#define TWO_PI_F 6.28318530717958647692f

#define NBLK 256                 // 1 block/CU, co-resident by construction
#define NTHR 256
#define NSCAN (NBLK * NTHR)      // 65536 scan threads
#define TOT4 (N_NODES * N_EDGES / 4)   // 2,097,152 float4s per matrix

// ---- device-coherent (cross-XCD) scalar access: bypass non-coherent L1/L2.
__device__ __forceinline__ float agent_load(const float* p) {
    return __hip_atomic_load(p, __ATOMIC_RELAXED, __HIP_MEMORY_SCOPE_AGENT);
}
__device__ __forceinline__ int agent_load_i(const int* p) {
    return __hip_atomic_load(p, __ATOMIC_RELAXED, __HIP_MEMORY_SCOPE_AGENT);
}
__device__ __forceinline__ void agent_store_i(int* p, int v) {
    __hip_atomic_store(p, v, __ATOMIC_RELAXED, __HIP_MEMORY_SCOPE_AGENT);
}
__device__ __forceinline__ void spin_ge(const int* p, int v) {
    while (__hip_atomic_load(p, __ATOMIC_RELAXED, __HIP_MEMORY_SCOPE_AGENT) < v)
        __builtin_amdgcn_s_sleep(2);
    asm volatile("" ::: "memory");
}

// ================= 16-amplitude 4-wire sub-circuit =================
// Bit map: wire W0->bit8, W1->bit4, W2->bit2, W3->bit1.
// Gate template (both circuit families factorize to this; verified
// gate-by-gate vs EDGE_OPS/NODE_OPS; r4-r6 bench absmax=0):
//   RY(t0,W0) RY(t1,W1) CX(W0,W1) RY(t2,W2) RY(t3,W3) CX(W3,W2)
//   RY(t4,W1) RY(t5,W2)
//   A-type: CX(W1,W2) RY(t6,W2)   -> returns <Z_W2>
//   B-type: CX(W2,W1) RY(t6,W1)   -> returns <Z_W1>, <X_W1>

template<int M>
__device__ __forceinline__ void ry16(float* a, float c, float s) {
#pragma unroll
    for (int i = 0; i < 16; ++i)
        if (!(i & M)) {
            int j = i | M;
            float x0 = a[i], x1 = a[j];
            a[i] = c * x0 - s * x1;
            a[j] = s * x0 + c * x1;
        }
}
template<int MC, int MT>
__device__ __forceinline__ void cx16(float* a) {
#pragma unroll
    for (int i = 0; i < 16; ++i)
        if ((i & MC) && !(i & MT)) {
            int j = i | MT;
            float t = a[i]; a[i] = a[j]; a[j] = t;
        }
}

template<bool BTYPE>
__device__ __forceinline__ void sub16(const float* ic, const float* is,
                                      const float* thc, const float* ths,
                                      float& z, float& x) {
    float a[16];
    a[0] = ic[3]; a[1] = is[3];
#pragma unroll
    for (int i = 0; i < 2; ++i) { a[i | 2] = a[i] * is[2]; a[i] *= ic[2]; }
#pragma unroll
    for (int i = 0; i < 4; ++i) { a[i | 4] = a[i] * is[1]; a[i] *= ic[1]; }
#pragma unroll
    for (int i = 0; i < 8; ++i) { a[i | 8] = a[i] * is[0]; a[i] *= ic[0]; }
    ry16<8>(a, thc[0], ths[0]);
    ry16<4>(a, thc[1], ths[1]);
    cx16<8, 4>(a);
    ry16<2>(a, thc[2], ths[2]);
    ry16<1>(a, thc[3], ths[3]);
    cx16<1, 2>(a);
    ry16<4>(a, thc[4], ths[4]);
    ry16<2>(a, thc[5], ths[5]);
    if (BTYPE) { cx16<2, 4>(a); ry16<4>(a, thc[6], ths[6]); }
    else       { cx16<4, 2>(a); ry16<2>(a, thc[6], ths[6]); }
    const int m = BTYPE ? 4 : 2;
    z = 0.f; x = 0.f;
#pragma unroll
    for (int i = 0; i < 16; ++i) z += (i & m) ? -a[i] * a[i] : a[i] * a[i];
    if (BTYPE) {
#pragma unroll
        for (int i = 0; i < 16; ++i) if (!(i & 4)) x += a[i] * a[i | 4];
        x *= 2.f;
    }
}

// node state update from gathered macc (identical op sequence in every
// replica -> bitwise-identical h across all edges touching this node):
// zB9 from OLD h-trig; then A1(mi),A2(mo); p9 -> new h; updates chh/shh.
__device__ __forceinline__ float node_update(
        const float* M, float& chh, float& shh,
        const float* cxv, const float* sxv,
        const float* tnC, const float* tnS, float C20, float S20) {
    float zB9, dmy;
    {   // B (h,x: wires 8-11): tn{8,9,10,11,16,17,21}, <Z9>
        float ic[4] = {chh, cxv[0], cxv[1], cxv[2]};
        float is[4] = {shh, sxv[0], sxv[1], sxv[2]};
        float thc[7] = {tnC[8],tnC[9],tnC[10],tnC[11],tnC[16],tnC[17],tnC[21]};
        float ths[7] = {tnS[8],tnS[9],tnS[10],tnS[11],tnS[16],tnS[17],tnS[21]};
        sub16<true>(ic, is, thc, ths, zB9, dmy);
    }
    float mC[8], mS[8];
#pragma unroll
    for (int k = 0; k < 8; ++k) __sincosf(0.5f * M[k], &mS[k], &mC[k]);
    float zA1, zA2, xA2;
    {   // A1 (mi, wires 0-3): tn{0,1,2,3,12,13,18}, <Z2>
        float thc[7] = {tnC[0],tnC[1],tnC[2],tnC[3],tnC[12],tnC[13],tnC[18]};
        float ths[7] = {tnS[0],tnS[1],tnS[2],tnS[3],tnS[12],tnS[13],tnS[18]};
        sub16<false>(&mC[0], &mS[0], thc, ths, zA1, dmy);
    }
    {   // A2 (mo, wires 4-7): tn{4,5,6,7,14,15,19}, <Z5>,<X5>
        float thc[7] = {tnC[4],tnC[5],tnC[6],tnC[7],tnC[14],tnC[15],tnC[19]};
        float ths[7] = {tnS[4],tnS[5],tnS[6],tnS[7],tnS[14],tnS[15],tnS[19]};
        sub16<true>(&mC[4], &mS[4], thc, ths, zA2, xA2);
    }
    float p9 = (C20*zA1*zA2 - S20*xA2) * zB9;
    float h = PI_F * (1.f - p9);
    __sincosf(0.5f*h, &shh, &chh);
    return h;
}

// edge scatter: mi[ri] += ev*Hs, mo[si] += ev*Hr; drain own vmem queue
// (atomics performed at coherence point), then tick both arrival counters.
__device__ __forceinline__ void scatter8(float ev, const float4& Hs, const float4& Hr,
                                         int si, int ri,
                                         float* __restrict__ macc, int* __restrict__ arr) {
    atomicAdd(&macc[ri*8+0], ev*Hs.x); atomicAdd(&macc[ri*8+1], ev*Hs.y);
    atomicAdd(&macc[ri*8+2], ev*Hs.z); atomicAdd(&macc[ri*8+3], ev*Hs.w);
    atomicAdd(&macc[si*8+4], ev*Hr.x); atomicAdd(&macc[si*8+5], ev*Hr.y);
    atomicAdd(&macc[si*8+6], ev*Hr.z); atomicAdd(&macc[si*8+7], ev*Hr.w);
    asm volatile("s_waitcnt vmcnt(0)" ::: "memory");
    atomicAdd(&arr[ri], 1); atomicAdd(&arr[si], 1);
}

// ================= single fused persistent kernel =================
// (r7 resubmission -- round 7 bench was an infra failure, no data)
// Phase 1 (ALL threads): scan Ri/Ro -> send/recv (value row+1) + deg;
//   drain; syncthreads; tick sdone.
// Phase 2 (wave 0 of blocks 0..63 = 4096 edge actors; NO node actors):
//   poll own cells (overlaps scan tail) -> local endpoint init -> it0
//   scatter -> wait sdone -> per round: poll arr, gather macc, REDUNDANTLY
//   recompute both endpoints' node update locally (bitwise-identical across
//   replicas), new ev -> scatter / out. Only ONE coherence hop per round.
__global__ __launch_bounds__(256) void k_fused(
        const float* __restrict__ X, const float* __restrict__ Ri,
        const float* __restrict__ Ro, const float* __restrict__ W,
        const float* __restrict__ b, const float* __restrict__ te,
        const float* __restrict__ tn,
        int* __restrict__ send, int* __restrict__ recv,
        float* __restrict__ maccA, float* __restrict__ maccB,
        int* __restrict__ arrA, int* __restrict__ arrB,
        int* __restrict__ deg, int* __restrict__ sdone,
        float* __restrict__ out) {
    __shared__ float s_teC[16], s_teS[16], s_tnC[24], s_tnS[24];
    int blk = blockIdx.x, tid = threadIdx.x;
    bool edge_blk = (blk < 64);

    if (edge_blk) {     // lane-uniform trig tables -> LDS (saves ~72 VGPR)
        if (tid < 14) {
            float s, c; __sincosf(0.5f * te[tid], &s, &c);
            s_teC[tid] = c; s_teS[tid] = s;
        } else if (tid == 14) {                    // full angle for ev combine
            float s, c; __sincosf(te[14], &s, &c);
            s_teC[14] = c; s_teS[14] = s;
        } else if (tid < 15 + 22) {
            int k = tid - 15; float s, c;
            if (k == 20) __sincosf(tn[20], &s, &c);        // full angle
            else         __sincosf(0.5f * tn[k], &s, &c);  // half angle
            s_tnC[k] = c; s_tnS[k] = s;
        }
    }

    // ---------------- phase 1: full-grid scan (16 loads in flight) --------
    {
        int gid = blk * NTHR + tid;
        const float4* Ri4 = (const float4*)Ri;
        const float4* Ro4 = (const float4*)Ro;
        // TOT4 = 4 * 8 * NSCAN exactly -> 4 iterations, no guards.
#pragma unroll 1
        for (int t0 = gid; t0 < TOT4; t0 += 8 * NSCAN) {
            float4 vi[8], vo[8];
#pragma unroll
            for (int u = 0; u < 8; ++u) {
                int t = t0 + u * NSCAN;
                vi[u] = Ri4[t]; vo[u] = Ro4[t];
            }
#pragma unroll
            for (int u = 0; u < 8; ++u) {
                int t = t0 + u * NSCAN;
                int base = t * 4;
                int row = base >> 12;              // 4096 floats per row
                int e   = base & (N_EDGES - 1);
                int cnt = 0;
                if (vi[u].x != 0.f) { agent_store_i(recv+e+0, row+1); ++cnt; }
                if (vi[u].y != 0.f) { agent_store_i(recv+e+1, row+1); ++cnt; }
                if (vi[u].z != 0.f) { agent_store_i(recv+e+2, row+1); ++cnt; }
                if (vi[u].w != 0.f) { agent_store_i(recv+e+3, row+1); ++cnt; }
                if (vo[u].x != 0.f) { agent_store_i(send+e+0, row+1); ++cnt; }
                if (vo[u].y != 0.f) { agent_store_i(send+e+1, row+1); ++cnt; }
                if (vo[u].z != 0.f) { agent_store_i(send+e+2, row+1); ++cnt; }
                if (vo[u].w != 0.f) { agent_store_i(send+e+3, row+1); ++cnt; }
                if (cnt) atomicAdd(&deg[row], cnt);
            }
        }
        asm volatile("s_waitcnt vmcnt(0)" ::: "memory");
        __syncthreads();                           // also publishes LDS trig
        if (tid == 0) atomicAdd(sdone, 1);
    }
    if (!edge_blk || tid >= 64) return;            // scanners + waves 1..3 exit

    // ================= EDGE actor: e = blk*64 + lane =================
    int e = blk * 64 + tid;

    // cells appear as the (possibly still-running) scan finds them
    int si, ri;
    {
        int v;
        while ((v = agent_load_i(send + e)) == 0) __builtin_amdgcn_s_sleep(1);
        si = v - 1;
        while ((v = agent_load_i(recv + e)) == 0) __builtin_amdgcn_s_sleep(1);
        ri = v - 1;
        asm volatile("" ::: "memory");
    }

    // local endpoint init (X/W/b immutable -> plain loads)
    float xs0 = X[si*3+0], xs1 = X[si*3+1], xs2 = X[si*3+2];
    float xr0 = X[ri*3+0], xr1 = X[ri*3+1], xr2 = X[ri*3+2];
    float w0 = W[0], w1 = W[1], w2 = W[2], bb = b[0];
    float hs = TWO_PI_F / (1.f + __expf(-(xs0*w0 + xs1*w1 + xs2*w2 + bb)));
    float hr = TWO_PI_F / (1.f + __expf(-(xr0*w0 + xr1*w1 + xr2*w2 + bb)));
    float chs, shs, chr, shr, cxs[3], sxs[3], cxr[3], sxr[3];
    __sincosf(0.5f*hs,  &shs,    &chs);
    __sincosf(0.5f*xs0, &sxs[0], &cxs[0]);
    __sincosf(0.5f*xs1, &sxs[1], &cxs[1]);
    __sincosf(0.5f*xs2, &sxs[2], &cxs[2]);
    __sincosf(0.5f*hr,  &shr,    &chr);
    __sincosf(0.5f*xr0, &sxr[0], &cxr[0]);
    __sincosf(0.5f*xr1, &sxr[1], &cxr[1]);
    __sincosf(0.5f*xr2, &sxr[2], &cxr[2]);
    float C14 = s_teC[14], S14 = s_teS[14];
    float C20 = s_tnC[20], S20 = s_tnS[20];

    float zA, zB, xB, dmy;
    {   // sender pub: A'-type, te{0,1,2,3,8,9,12}, <Z2>
        float ic[4] = {chs, cxs[0], cxs[1], cxs[2]};
        float is[4] = {shs, sxs[0], sxs[1], sxs[2]};
        float thc[7] = {s_teC[0],s_teC[1],s_teC[2],s_teC[3],s_teC[8],s_teC[9],s_teC[12]};
        float ths[7] = {s_teS[0],s_teS[1],s_teS[2],s_teS[3],s_teS[8],s_teS[9],s_teS[12]};
        sub16<false>(ic, is, thc, ths, zA, dmy);
    }
    {   // receiver pub: B'-type, te{4,5,6,7,10,11,13}, <Z5>,<X5>
        float ic[4] = {chr, cxr[0], cxr[1], cxr[2]};
        float is[4] = {shr, sxr[0], sxr[1], sxr[2]};
        float thc[7] = {s_teC[4],s_teC[5],s_teC[6],s_teC[7],s_teC[10],s_teC[11],s_teC[13]};
        float ths[7] = {s_teS[4],s_teS[5],s_teS[6],s_teS[7],s_teS[10],s_teS[11],s_teS[13]};
        sub16<true>(ic, is, thc, ths, zB, xB);
    }
    float ev = 0.5f*(1.f - (C14*zA*zB - S14*xB));
    // it0 scatter may run before sdone: macc/arr pre-zeroed by the memset,
    // and deg is only READ (below) after sdone.
    scatter8(ev, make_float4(hs, xs0, xs1, xs2),
                 make_float4(hr, xr0, xr1, xr2), si, ri, maccA, arrA);

    spin_ge(sdone, NBLK);                          // deg final everywhere
    int dgs = agent_load_i(deg + si);
    int dgr = agent_load_i(deg + ri);

#pragma unroll
    for (int it = 0; it < 2; ++it) {
        const float* mc_ = it ? maccB : maccA;
        const int*   ar  = it ? arrB  : arrA;
        // single coherence hop: all my endpoints' edges have scattered
        while (agent_load_i(ar + si) < dgs || agent_load_i(ar + ri) < dgr)
            __builtin_amdgcn_s_sleep(1);
        asm volatile("" ::: "memory");
        float Ms[8], Mr[8];
#pragma unroll
        for (int k = 0; k < 8; ++k) Ms[k] = agent_load(mc_ + si*8 + k);
#pragma unroll
        for (int k = 0; k < 8; ++k) Mr[k] = agent_load(mc_ + ri*8 + k);
        hs = node_update(Ms, chs, shs, cxs, sxs, s_tnC, s_tnS, C20, S20);
        hr = node_update(Mr, chr, shr, cxr, sxr, s_tnC, s_tnS, C20, S20);
        {   // new sender pub
            float ic[4] = {chs, cxs[0], cxs[1], cxs[2]};
            float is[4] = {shs, sxs[0], sxs[1], sxs[2]};
            float thc[7] = {s_teC[0],s_teC[1],s_teC[2],s_teC[3],s_teC[8],s_teC[9],s_teC[12]};
            float ths[7] = {s_teS[0],s_teS[1],s_teS[2],s_teS[3],s_teS[8],s_teS[9],s_teS[12]};
            sub16<false>(ic, is, thc, ths, zA, dmy);
        }
        {   // new receiver pub
            float ic[4] = {chr, cxr[0], cxr[1], cxr[2]};
            float is[4] = {shr, sxr[0], sxr[1], sxr[2]};
            float thc[7] = {s_teC[4],s_teC[5],s_teC[6],s_teC[7],s_teC[10],s_teC[11],s_teC[13]};
            float ths[7] = {s_teS[4],s_teS[5],s_teS[6],s_teS[7],s_teS[10],s_teS[11],s_teS[13]};
            sub16<true>(ic, is, thc, ths, zB, xB);
        }
        ev = 0.5f*(1.f - (C14*zA*zB - S14*xB));
        if (it == 0) {
            scatter8(ev, make_float4(hs, xs0, xs1, xs2),
                         make_float4(hr, xr0, xr1, xr2), si, ri, maccB, arrB);
        } else {
            out[e] = ev;
        }
    }
}

extern "C" void kernel_launch(void* const* d_in, const int* in_sizes, int n_in,
                              void* d_out, int out_size, void* d_ws, size_t ws_size,
                              hipStream_t stream) {
    const float* X  = (const float*)d_in[0];
    const float* Ri = (const float*)d_in[1];
    const float* Ro = (const float*)d_in[2];
    const float* W  = (const float*)d_in[3];
    const float* b  = (const float*)d_in[4];
    const float* te = (const float*)d_in[5];
    const float* tn = (const float*)d_in[6];
    float* out = (float*)d_out;

    // ---- zero region: one memset covers everything (no H/pub needed) ----
    int*   send  = (int*)d_ws;                      // [4096] holds row+1
    int*   recv  = send + N_EDGES;                  // [4096]
    float* maccA = (float*)(recv + N_EDGES);        // [16384]
    float* maccB = maccA + N_NODES * 8;             // [16384]
    int*   arrA  = (int*)(maccB + N_NODES * 8);     // [2048]
    int*   arrB  = arrA + N_NODES;                  // [2048]
    int*   deg   = arrB + N_NODES;                  // [2048]
    int*   sdone = deg + N_NODES;                   // [16]
    size_t zbytes = (size_t)(2*N_EDGES + 2*N_NODES*8 + 3*N_NODES + 16) * 4;

    hipMemsetAsync((void*)send, 0, zbytes, stream);
    k_fused<<<NBLK, NTHR, 0, stream>>>(X, Ri, Ro, W, b, te, tn,
                                       send, recv, maccA, maccB,
                                       arrA, arrB, deg, sdone, out);
}